// Round 21
// baseline (221.519 us; speedup 1.0000x reference)
//
#include <hip/hip_runtime.h>
#include <hip/hip_bf16.h>

#define DEV static __device__ __forceinline__

typedef __bf16 bf16x8 __attribute__((ext_vector_type(8)));
typedef unsigned short u16x8 __attribute__((ext_vector_type(8)));
typedef unsigned short u16x4 __attribute__((ext_vector_type(4)));
typedef float f32x4 __attribute__((ext_vector_type(4)));

#if __has_builtin(__builtin_amdgcn_exp2f)
#define EXP2F(x) __builtin_amdgcn_exp2f(x)
#else
#define EXP2F(x) exp2f(x)
#endif
#if __has_builtin(__builtin_amdgcn_rcpf)
#define RCPF(x) __builtin_amdgcn_rcpf(x)
#else
#define RCPF(x) (1.0f / (x))
#endif

// ---------- helpers ----------

DEV unsigned short f2bfh(float f) {
    return __builtin_bit_cast(unsigned short, (__bf16)f);
}

DEV float bf2f(unsigned short v) {
    return __builtin_bit_cast(float, (unsigned)v << 16);
}

DEV float gelu_f(float x) {
    float x2 = x * x;
    float t  = __builtin_fmaf(-0.10294324f, x2, -2.3022082f);
    float e  = EXP2F(x * t);
    return x * RCPF(1.0f + e);
}

DEV f32x4 mfma16(bf16x8 a, bf16x8 b, f32x4 c) {
    return __builtin_amdgcn_mfma_f32_16x16x32_bf16(a, b, c, 0, 0, 0);
}

DEV bf16x8 cvt8(float4 x, float4 y) {
    bf16x8 r;
    r[0] = (__bf16)x.x; r[1] = (__bf16)x.y; r[2] = (__bf16)x.z; r[3] = (__bf16)x.w;
    r[4] = (__bf16)y.x; r[5] = (__bf16)y.y; r[6] = (__bf16)y.z; r[7] = (__bf16)y.w;
    return r;
}

DEV bf16x8 aload_f32(const float* p) {
    float4 x = *(const float4*)p;
    float4 y = *(const float4*)(p + 4);
    return cvt8(x, y);
}

DEV bf16x8 uload(const unsigned short* p) {
    return __builtin_bit_cast(bf16x8, *(const u16x8*)(p));
}

DEV bf16x8 bload(const unsigned short* WT, int col, int koff) {
    return __builtin_bit_cast(bf16x8, *(const u16x8*)(WT + col * 136 + koff));
}

DEV void stage_wt(unsigned short* WT, const unsigned short* src, int tid, int nthr) {
    for (int i = tid; i < 2048; i += nthr) {
        int n = i >> 4, k0 = (i & 15) << 3;
        *(u16x8*)(WT + n * 136 + k0) = *(const u16x8*)(src + n * 128 + k0);
    }
}

// direct global -> LDS, 16 B per lane. Dest = wave-uniform base + lane*16.
DEV void gload16(const void* g, void* lds) {
    __builtin_amdgcn_global_load_lds(
        (const __attribute__((address_space(1))) unsigned*)g,
        (__attribute__((address_space(3))) unsigned*)lds, 16, 0, 0);
}

// ---------- weight pre-transpose ----------
__global__ __launch_bounds__(256) void k_wconv(
    const float* __restrict__ smW1, const float* __restrict__ smW2,
    const float* __restrict__ projW, const float* __restrict__ msgW1,
    const float* __restrict__ msgW2, const float* __restrict__ ffnW1,
    const float* __restrict__ ffnW2, unsigned short* __restrict__ WTG)
{
    int m = blockIdx.x >> 3;
    int chunk = blockIdx.x & 7;
    const float* src;
    if (m == 0) src = smW1;
    else if (m == 1) src = smW1 + 16384;
    else if (m == 2) src = smW2;
    else if (m == 3) src = projW;
    else {
        int mm = m - 4; int l = mm / 6; int j = mm % 6;
        if (j < 3)      src = msgW1 + l * 49152 + j * 16384;
        else if (j == 3) src = msgW2 + l * 16384;
        else if (j == 4) src = ffnW1 + l * 16384;
        else             src = ffnW2 + l * 16384;
    }
    unsigned short* dst = WTG + m * 16384;
    int s0 = chunk * 2048 + threadIdx.x * 8;
    int k = s0 >> 7, n = s0 & 127;
    float4 x = *(const float4*)(src + s0);
    float4 y = *(const float4*)(src + s0 + 4);
    dst[(n + 0) * 128 + k] = f2bfh(x.x);
    dst[(n + 1) * 128 + k] = f2bfh(x.y);
    dst[(n + 2) * 128 + k] = f2bfh(x.z);
    dst[(n + 3) * 128 + k] = f2bfh(x.w);
    dst[(n + 4) * 128 + k] = f2bfh(y.x);
    dst[(n + 5) * 128 + k] = f2bfh(y.y);
    dst[(n + 6) * 128 + k] = f2bfh(y.z);
    dst[(n + 7) * 128 + k] = f2bfh(y.w);
}

// ---------- time features + adaLN modulation ----------
__global__ __launch_bounds__(256) void k_prep(
    const float* __restrict__ t,
    const float* __restrict__ smadaW, const float* __restrict__ smadab,
    const float* __restrict__ a1W, const float* __restrict__ a1b,
    const float* __restrict__ a2W, const float* __restrict__ a2b,
    float* __restrict__ MOD)
{
    __shared__ float tf[4][128];
    int tid = threadIdx.x;
    {
        int b = tid >> 6, i = tid & 63;
        float wn = __expf(-(float)i * (9.210340371976184f / 64.0f));
        float ph = t[b] * wn;
        tf[b][2 * i]     = sinf(ph);
        tf[b][2 * i + 1] = cosf(ph);
    }
    __syncthreads();
    int o = blockIdx.x * 256 + tid;
    int b, c;
    const float* W; const float* bias; float* out;
    if (o < 1024) {
        b = o >> 8; c = o & 255; W = smadaW; bias = smadab; out = MOD + o;
    } else if (o < 4096) {
        int oo = o - 1024; int lb = oo >> 8; int l = lb >> 2;
        b = lb & 3; c = oo & 255;
        W = a1W + l * 32768; bias = a1b + l * 256; out = MOD + o;
    } else {
        int oo = o - 4096; int lb = oo >> 8; int l = lb >> 2;
        b = lb & 3; c = oo & 255;
        W = a2W + l * 32768; bias = a2b + l * 256; out = MOD + 4096 + oo;
    }
    float s = bias[c];
    const float* tfb = tf[b];
    #pragma unroll 8
    for (int k = 0; k < 128; ++k) s += tfb[k] * W[k * 256 + c];
    *out = s;
}

// ---------- sequence messenger MLP + adaLN -> Vbuf (128 thr, 32 tok, grid 256) ----------
__global__ __launch_bounds__(128) void k_msgr(
    const float* __restrict__ V, const float* __restrict__ Z,
    const unsigned short* __restrict__ WTG,
    const float* __restrict__ smb1, const float* __restrict__ smb2,
    const float* __restrict__ MOD, float* __restrict__ Vout)
{
    __shared__ __align__(16) unsigned short WT[128 * 136];
    __shared__ __align__(16) float XB[32 * 132];
    const int tid = threadIdx.x;
    const int w = tid >> 6, l = tid & 63, lr = l & 15, lg = l >> 4;
    const int tok0 = blockIdx.x * 32;
    const int batch = tok0 >> 11;
    const int rowA = tok0 + w * 16 + lr;

    f32x4 acc[8] = {};
    for (int kh = 0; kh < 2; ++kh) {
        __syncthreads();
        stage_wt(WT, WTG + kh * 16384, tid, 128);
        __syncthreads();
        const float* A = (kh == 0) ? V : Z;
        #pragma unroll
        for (int ks = 0; ks < 4; ++ks) {
            bf16x8 a = aload_f32(A + rowA * 128 + ks * 32 + lg * 8);
            #pragma unroll
            for (int c = 0; c < 8; ++c)
                acc[c] = mfma16(a, bload(WT, c * 16 + lr, ks * 32 + lg * 8), acc[c]);
        }
    }
    #pragma unroll
    for (int c = 0; c < 8; ++c) {
        int col = c * 16 + lr;
        float b1v = smb1[col];
        #pragma unroll
        for (int j = 0; j < 4; ++j)
            XB[(w * 16 + lg * 4 + j) * 132 + col] = gelu_f(acc[c][j] + b1v);
    }
    __syncthreads();
    stage_wt(WT, WTG + 2 * 16384, tid, 128);
    __syncthreads();
    f32x4 acc2[8] = {};
    #pragma unroll
    for (int ks = 0; ks < 4; ++ks) {
        bf16x8 a = aload_f32(XB + (w * 16 + lr) * 132 + ks * 32 + lg * 8);
        #pragma unroll
        for (int c = 0; c < 8; ++c)
            acc2[c] = mfma16(a, bload(WT, c * 16 + lr, ks * 32 + lg * 8), acc2[c]);
    }
    const float* MODp = MOD + batch * 256;
    #pragma unroll
    for (int j = 0; j < 4; ++j) {
        int row = tok0 + w * 16 + lg * 4 + j;
        float xv[8], s1 = 0.f, s2 = 0.f;
        #pragma unroll
        for (int c = 0; c < 8; ++c) {
            int col = c * 16 + lr;
            float x = acc2[c][j] + smb2[col] + V[row * 128 + col];
            xv[c] = x; s1 += x; s2 += x * x;
        }
        #pragma unroll
        for (int m = 1; m <= 8; m <<= 1) { s1 += __shfl_xor(s1, m); s2 += __shfl_xor(s2, m); }
        float mu = s1 * (1.0f / 128.0f);
        float var = s2 * (1.0f / 128.0f) - mu * mu;
        float rs = rsqrtf(var + 1e-5f);
        #pragma unroll
        for (int c = 0; c < 8; ++c) {
            int col = c * 16 + lr;
            Vout[row * 128 + col] = (xv[c] - mu) * rs * (1.0f + MODp[col]) + MODp[128 + col];
        }
    }
}

// ---------- per-layer: TA = V@W1a + b1 (f32) OR TB = V@W1c (bf16), grid 256 ----------
__global__ __launch_bounds__(256) void k_tab(
    const float* __restrict__ Vb, const unsigned short* __restrict__ WTa,
    const unsigned short* __restrict__ WTc, const float* __restrict__ b1,
    float* __restrict__ TAf, unsigned short* __restrict__ TBb)
{
    __shared__ __align__(16) unsigned short WT[128 * 136];
    const int tid = threadIdx.x;
    const int w = tid >> 6, l = tid & 63, lr = l & 15, lg = l >> 4;
    const int half = blockIdx.x >> 7;                 // 0: TA, 1: TB
    const int tok0 = (blockIdx.x & 127) * 64;
    const int rowA = tok0 + w * 16 + lr;

    stage_wt(WT, half ? WTc : WTa, tid, 256);
    __syncthreads();
    f32x4 acc[8] = {};
    #pragma unroll
    for (int ks = 0; ks < 4; ++ks) {
        bf16x8 a = aload_f32(Vb + rowA * 128 + ks * 32 + lg * 8);
        #pragma unroll
        for (int c = 0; c < 8; ++c)
            acc[c] = mfma16(a, bload(WT, c * 16 + lr, ks * 32 + lg * 8), acc[c]);
    }
    if (half == 0) {
        #pragma unroll
        for (int c = 0; c < 8; ++c) {
            int col = c * 16 + lr;
            float b1v = b1[col];
            #pragma unroll
            for (int j = 0; j < 4; ++j) {
                int row = tok0 + w * 16 + lg * 4 + j;
                TAf[row * 128 + col] = acc[c][j] + b1v;
            }
        }
    } else {
        #pragma unroll
        for (int c = 0; c < 8; ++c) {
            int col = c * 16 + lr;
            #pragma unroll
            for (int j = 0; j < 4; ++j) {
                int row = tok0 + w * 16 + lg * 4 + j;
                TBb[row * 128 + col] = f2bfh(acc[c][j]);
            }
        }
    }
}

// ---------- PRODUCTION edge kernel (R18/R20 best): counted-vmcnt dbuf (MODE 3) ----------
template<int MODE>
__global__ __launch_bounds__(256, 2) void k_edge16(
    const float* __restrict__ E,              // f32 [8192][30][128]
    const unsigned short* __restrict__ Ebf,   // bf16 PLAIN [8192][32][128] (MODE 3)
    unsigned short* __restrict__ EbfW,        // writeback target (MODE 1)
    const int* __restrict__ Kidx, const float* __restrict__ TAf,
    const unsigned short* __restrict__ TBb,   // bf16 PLAIN [8192][128]
    const unsigned short* __restrict__ WTb, float* __restrict__ S)
{
    __shared__ __align__(16) unsigned short ELb[2][32 * 128];   // 2 x 8192 B
    __shared__ __align__(16) unsigned short TBL[2][32 * 128];   // 2 x 8192 B
    const int tid = threadIdx.x;
    const int w = tid >> 6, l = tid & 63, lr = l & 15, lg = l >> 4;
    const int nq = w;
    const int t0 = blockIdx.x * 4;
    const int bbase = (t0 >> 11) << 11;

    // loop-invariant B fragments: cols [nq*32, nq*32+32), 32 VGPR, L2-hot
    bf16x8 bfr[8];
    #pragma unroll
    for (int n = 0; n < 2; ++n)
        #pragma unroll
        for (int ks = 0; ks < 4; ++ks)
            bfr[n * 4 + ks] = uload(WTb + (nq * 32 + n * 16 + lr) * 128 + ks * 32 + lg * 8);

    float4 eR[4];   // MODE<3 staging regs
    int kc[2];

    auto KREAD2 = [&](int tok, int k[2]) {
        #pragma unroll
        for (int it = 0; it < 2; ++it) {
            int r = (it * 256 + tid) >> 4;
            k[it] = (r < 30) ? Kidx[tok * 30 + r] : 0;
        }
    };
    auto TBGLOAD = [&](int buf, const int k[2]) {
        #pragma unroll
        for (int it = 0; it < 2; ++it) {
            int s = it * 256 + tid;
            int r = s >> 4, q = s & 15;
            const char* src = (const char*)(TBb + (size_t)(bbase + k[it]) * 128)
                            + (((q ^ (r & 7)) << 4));
            gload16(src, (char*)TBL[buf] + it * 4096 + (w << 10));
        }
    };
    auto EGLOAD = [&](int buf, int tok) {
        #pragma unroll
        for (int it = 0; it < 2; ++it) {
            int s = it * 256 + tid;
            int r = s >> 4, q = s & 15;
            const char* src = (const char*)Ebf + (size_t)tok * 8192 + r * 256
                            + (((q ^ (r & 7)) << 4));
            gload16(src, (char*)ELb[buf] + it * 4096 + (w << 10));
        }
    };
    auto EISSUE = [&](int tok) {
        #pragma unroll
        for (int it = 0; it < 4; ++it) {
            int s = it * 256 + tid;
            if (s < 960)
                eR[it] = *(const float4*)(E + ((size_t)tok * 30 + (s >> 5)) * 128 + (s & 31) * 4);
        }
    };
    auto SWRITE_E = [&](int buf, int tok) {
        #pragma unroll
        for (int it = 0; it < 4; ++it) {
            int s = it * 256 + tid;
            if (s < 960) {
                int rr = s >> 5, q = s & 31;
                u16x4 pk;
                pk[0] = f2bfh(eR[it].x); pk[1] = f2bfh(eR[it].y);
                pk[2] = f2bfh(eR[it].z); pk[3] = f2bfh(eR[it].w);
                *(u16x4*)((char*)ELb[buf] + rr * 256 + ((q * 8) ^ ((rr & 7) << 4))) = pk;
                if constexpr (MODE == 1)
                    *(u16x4*)((char*)EbfW + (size_t)tok * 8192 + rr * 256 + q * 8) = pk;
            } else if constexpr (MODE == 1) {
                int rr = s >> 5, q = s & 31;
                u16x4 z = {0, 0, 0, 0};
                *(u16x4*)((char*)EbfW + (size_t)tok * 8192 + rr * 256 + q * 8) = z;
            }
        }
    };
    auto COMPUTE = [&](int tok, int cur) {
        float ta[2];
        #pragma unroll
        for (int n = 0; n < 2; ++n) ta[n] = TAf[tok * 128 + nq * 32 + n * 16 + lr];
        float sacc[2] = {0.f, 0.f};
        const char* eb  = (const char*)ELb[cur];
        const char* tbb = (const char*)TBL[cur];
        #pragma unroll
        for (int m = 0; m < 2; ++m) {
            bf16x8 ar[4];
            #pragma unroll
            for (int ks = 0; ks < 4; ++ks)
                ar[ks] = *(const bf16x8*)(eb + (m * 16 + lr) * 256 +
                          (((ks * 32 + lg * 8) * 2) ^ ((lr & 7) << 4)));
            f32x4 acc[2] = {};
            #pragma unroll
            for (int ks = 0; ks < 4; ++ks)
                #pragma unroll
                for (int n = 0; n < 2; ++n)
                    acc[n] = mfma16(ar[ks], bfr[n * 4 + ks], acc[n]);
            #pragma unroll
            for (int n = 0; n < 2; ++n) {
                int c2 = (nq * 32 + n * 16 + lr) * 2;
                #pragma unroll
                for (int j = 0; j < 4; ++j) {
                    int r = m * 16 + lg * 4 + j;
                    if (r < 30) {
                        unsigned short uv = *(const unsigned short*)(tbb + r * 256 + (c2 ^ ((r & 7) << 4)));
                        sacc[n] += gelu_f(acc[n][j] + ta[n] + bf2f(uv));
                    }
                }
            }
        }
        #pragma unroll
        for (int n = 0; n < 2; ++n) {
            sacc[n] += __shfl_xor(sacc[n], 16);
            sacc[n] += __shfl_xor(sacc[n], 32);
        }
        if (l < 16) {
            #pragma unroll
            for (int n = 0; n < 2; ++n)
                S[tok * 128 + nq * 32 + n * 16 + l] = sacc[n];
        }
    };

    if constexpr (MODE == 3) {
        // Kidx for all 4 tokens prefetched into registers (statically indexed)
        int k0[2], k1[2], k2[2], k3[2];
        KREAD2(t0 + 0, k0);
        KREAD2(t0 + 1, k1);
        KREAD2(t0 + 2, k2);
        KREAD2(t0 + 3, k3);
        EGLOAD(0, t0);
        TBGLOAD(0, k0);

#define EDGE_STEP(I, KNEXT, WAITSTR)                                     \
        {                                                                \
            if constexpr ((I) + 1 <= 3) {                                \
                TBGLOAD(((I) + 1) & 1, KNEXT);                           \
                EGLOAD(((I) + 1) & 1, t0 + (I) + 1);                     \
            }                                                            \
            asm volatile("s_waitcnt vmcnt(" WAITSTR ")" ::: "memory");   \
            __builtin_amdgcn_sched_barrier(0);                           \
            __builtin_amdgcn_s_barrier();                                \
            __builtin_amdgcn_sched_barrier(0);                           \
            COMPUTE(t0 + (I), (I) & 1);                                  \
            if constexpr ((I) < 3) {                                     \
                __builtin_amdgcn_sched_barrier(0);                       \
                __builtin_amdgcn_s_barrier();                            \
                __builtin_amdgcn_sched_barrier(0);                       \
            }                                                            \
        }
        EDGE_STEP(0, k1, "4")
        EDGE_STEP(1, k2, "4")
        EDGE_STEP(2, k3, "4")
        EDGE_STEP(3, k3, "0")
#undef EDGE_STEP
    } else {
        // ---- layer-0 path (reg-staged E + Ebf writeback): safe __syncthreads ----
        int ka[2];
        EISSUE(t0);
        KREAD2(t0, ka);
        SWRITE_E(0, t0);
        TBGLOAD(0, ka);
        EISSUE(t0 + 1);
        KREAD2(t0 + 1, kc);
        __syncthreads();

        #pragma unroll 1
        for (int i = 0; i < 4; ++i) {
            if (i + 1 <= 3) {
                int bufn = (i + 1) & 1;
                SWRITE_E(bufn, t0 + i + 1);
                TBGLOAD(bufn, kc);
                if (i + 2 <= 3) { EISSUE(t0 + i + 2); KREAD2(t0 + i + 2, kc); }
            }
            COMPUTE(t0 + i, i & 1);
            if (i < 3) __syncthreads();
        }
    }
}

// ---------- per-layer token kernel (128 thr, 32 tok, grid 256) ----------
__global__ __launch_bounds__(128) void k_token(
    const float* __restrict__ Sb, const float* __restrict__ Vb,
    const unsigned short* __restrict__ WTW2, const float* __restrict__ b2,
    const unsigned short* __restrict__ WTF1, const float* __restrict__ fb1,
    const unsigned short* __restrict__ WTF2, const float* __restrict__ fb2,
    const unsigned short* __restrict__ WTP,
    const float* __restrict__ MOD1, const float* __restrict__ MOD2,
    float* __restrict__ Vout, int final_)
{
    __shared__ __align__(16) unsigned short WT[128 * 136];
    __shared__ __align__(16) float XB[32 * 132];
    const int tid = threadIdx.x;
    const int w = tid >> 6, l = tid & 63, lr = l & 15, lg = l >> 4;
    const int tok0 = blockIdx.x * 32;
    const int batch = tok0 >> 11;
    const int rloc = w * 16 + lr;

    stage_wt(WT, WTW2, tid, 128);
    __syncthreads();
    f32x4 acc[8] = {};
    #pragma unroll
    for (int ks = 0; ks < 4; ++ks) {
        bf16x8 a = aload_f32(Sb + (tok0 + rloc) * 128 + ks * 32 + lg * 8);
        #pragma unroll
        for (int c = 0; c < 8; ++c)
            acc[c] = mfma16(a, bload(WT, c * 16 + lr, ks * 32 + lg * 8), acc[c]);
    }
    const float* M1 = MOD1 + batch * 256;
    const float* M2 = MOD2 + batch * 256;
    float vp[8][4];
    #pragma unroll
    for (int j = 0; j < 4; ++j) {
        int row = tok0 + w * 16 + lg * 4 + j;
        float xv[8], s1 = 0.f, s2 = 0.f;
        #pragma unroll
        for (int c = 0; c < 8; ++c) {
            int col = c * 16 + lr;
            float x = acc[c][j] * (1.0f / 30.0f) + b2[col] + Vb[row * 128 + col];
            xv[c] = x; s1 += x; s2 += x * x;
        }
        #pragma unroll
        for (int m = 1; m <= 8; m <<= 1) { s1 += __shfl_xor(s1, m); s2 += __shfl_xor(s2, m); }
        float mu = s1 * (1.0f / 128.0f);
        float var = s2 * (1.0f / 128.0f) - mu * mu;
        float rs = rsqrtf(var + 1e-5f);
        #pragma unroll
        for (int c = 0; c < 8; ++c) {
            int col = c * 16 + lr;
            vp[c][j] = (xv[c] - mu) * rs * (1.0f + M1[col]) + M1[128 + col];
        }
    }
    __syncthreads();
    #pragma unroll
    for (int c = 0; c < 8; ++c)
        #pragma unroll
        for (int j = 0; j < 4; ++j)
            XB[(w * 16 + lg * 4 + j) * 132 + c * 16 + lr] = vp[c][j];
    stage_wt(WT, WTF1, tid, 128);
    __syncthreads();
    f32x4 accB[8] = {};
    #pragma unroll
    for (int ks = 0; ks < 4; ++ks) {
        bf16x8 a = aload_f32(XB + rloc * 132 + ks * 32 + lg * 8);
        #pragma unroll
        for (int c = 0; c < 8; ++c)
            accB[c] = mfma16(a, bload(WT, c * 16 + lr, ks * 32 + lg * 8), accB[c]);
    }
    __syncthreads();
    #pragma unroll
    for (int c = 0; c < 8; ++c) {
        int col = c * 16 + lr;
        float bv = fb1[col];
        #pragma unroll
        for (int j = 0; j < 4; ++j)
            XB[(w * 16 + lg * 4 + j) * 132 + col] = gelu_f(accB[c][j] + bv);
    }
    stage_wt(WT, WTF2, tid, 128);
    __syncthreads();
    f32x4 accC[8] = {};
    #pragma unroll
    for (int ks = 0; ks < 4; ++ks) {
        bf16x8 a = aload_f32(XB + rloc * 132 + ks * 32 + lg * 8);
        #pragma unroll
        for (int c = 0; c < 8; ++c)
            accC[c] = mfma16(a, bload(WT, c * 16 + lr, ks * 32 + lg * 8), accC[c]);
    }
    float v2[8][4];
    #pragma unroll
    for (int j = 0; j < 4; ++j) {
        float xv[8], s1 = 0.f, s2 = 0.f;
        #pragma unroll
        for (int c = 0; c < 8; ++c) {
            int col = c * 16 + lr;
            float x = accC[c][j] + fb2[col] + vp[c][j];
            xv[c] = x; s1 += x; s2 += x * x;
        }
        #pragma unroll
        for (int m = 1; m <= 8; m <<= 1) { s1 += __shfl_xor(s1, m); s2 += __shfl_xor(s2, m); }
        float mu = s1 * (1.0f / 128.0f);
        float var = s2 * (1.0f / 128.0f) - mu * mu;
        float rs = rsqrtf(var + 1e-5f);
        #pragma unroll
        for (int c = 0; c < 8; ++c) {
            int col = c * 16 + lr;
            v2[c][j] = (xv[c] - mu) * rs * (1.0f + M2[col]) + M2[128 + col];
        }
    }
    if (!final_) {
        #pragma unroll
        for (int c = 0; c < 8; ++c)
            #pragma unroll
            for (int j = 0; j < 4; ++j)
                Vout[(tok0 + w * 16 + lg * 4 + j) * 128 + c * 16 + lr] = v2[c][j];
    } else {
        __syncthreads();
        #pragma unroll
        for (int c = 0; c < 8; ++c)
            #pragma unroll
            for (int j = 0; j < 4; ++j)
                XB[(w * 16 + lg * 4 + j) * 132 + c * 16 + lr] = v2[c][j];
        stage_wt(WT, WTP, tid, 128);
        __syncthreads();
        f32x4 accD[8] = {};
        #pragma unroll
        for (int ks = 0; ks < 4; ++ks) {
            bf16x8 a = aload_f32(XB + rloc * 132 + ks * 32 + lg * 8);
            #pragma unroll
            for (int c = 0; c < 8; ++c)
                accD[c] = mfma16(a, bload(WT, c * 16 + lr, ks * 32 + lg * 8), accD[c]);
        }
        #pragma unroll
        for (int c = 0; c < 8; ++c)
            #pragma unroll
            for (int j = 0; j < 4; ++j)
                Vout[(tok0 + w * 16 + lg * 4 + j) * 128 + c * 16 + lr] = accD[c][j];
    }
}

// ---------- host ----------

extern "C" void kernel_launch(void* const* d_in, const int* in_sizes, int n_in,
                              void* d_out, int out_size, void* d_ws, size_t ws_size,
                              hipStream_t stream)
{
    const float* V     = (const float*)d_in[0];
    const float* E     = (const float*)d_in[1];
    const int*   K     = (const int*)d_in[2];
    const float* Z     = (const float*)d_in[3];
    const float* t     = (const float*)d_in[4];
    const float* smW1   = (const float*)d_in[6];
    const float* smb1   = (const float*)d_in[7];
    const float* smW2   = (const float*)d_in[8];
    const float* smb2   = (const float*)d_in[9];
    const float* smadaW = (const float*)d_in[10];
    const float* smadab = (const float*)d_in[11];
    const float* msgW1  = (const float*)d_in[12];
    const float* msgb1  = (const float*)d_in[13];
    const float* msgW2  = (const float*)d_in[14];
    const float* msgb2  = (const float*)d_in[15];
    const float* a1W    = (const float*)d_in[16];
    const float* a1b    = (const float*)d_in[17];
    const float* fW1    = (const float*)d_in[18];
    const float* fb1    = (const float*)d_in[19];
    const float* fW2    = (const float*)d_in[20];
    const float* fb2    = (const float*)d_in[21];
    const float* a2W    = (const float*)d_in[22];
    const float* a2b    = (const float*)d_in[23];
    const float* projW  = (const float*)d_in[24];

    float* Vbuf = (float*)d_ws;                            // 8192*128 f32
    float* TAf  = Vbuf + 8192 * 128;                       // 8192*128 f32
    float* Sb   = TAf + 8192 * 128;                        // 8192*128 f32
    float* MOD  = Sb + 8192 * 128;                         // 7168 f32
    unsigned short* TBb = (unsigned short*)(MOD + 7168);   // 8192*128 u16
    unsigned short* WTG = TBb + 8192 * 128;                // 22*16384 u16
    unsigned short* Ebf = WTG + 22 * 16384;                // 8192*4096 u16 (64 MB)

    size_t need = (size_t)(3 * 8192 * 128 + 7168) * 4
                + (size_t)(8192 * 128 + 22 * 16384) * 2
                + (size_t)8192 * 4096 * 2;
    const bool ebf_ok = (ws_size >= need);

    k_wconv<<<dim3(176), dim3(256), 0, stream>>>(smW1, smW2, projW, msgW1, msgW2, fW1, fW2, WTG);
    k_prep<<<dim3(28), dim3(256), 0, stream>>>(t, smadaW, smadab, a1W, a1b, a2W, a2b, MOD);
    k_msgr<<<dim3(256), dim3(128), 0, stream>>>(V, Z, WTG, smb1, smb2, MOD, Vbuf);

    for (int l = 0; l < 3; ++l) {
        const unsigned short* Wl = WTG + (4 + l * 6) * 16384;
        k_tab<<<dim3(256), dim3(256), 0, stream>>>(Vbuf, Wl, Wl + 2 * 16384, msgb1 + l * 128, TAf, TBb);
        if (ebf_ok) {
            if (l == 0)
                k_edge16<1><<<dim3(2048), dim3(256), 0, stream>>>(
                    E, Ebf, Ebf, K, TAf, TBb, Wl + 16384, Sb);
            else
                k_edge16<3><<<dim3(2048), dim3(256), 0, stream>>>(
                    E, Ebf, Ebf, K, TAf, TBb, Wl + 16384, Sb);
        } else {
            k_edge16<0><<<dim3(2048), dim3(256), 0, stream>>>(
                E, Ebf, Ebf, K, TAf, TBb, Wl + 16384, Sb);
        }
        int fin = (l == 2);
        k_token<<<dim3(256), dim3(128), 0, stream>>>(
            Sb, Vbuf, Wl + 3 * 16384, msgb2 + l * 128,
            Wl + 4 * 16384, fb1 + l * 128, Wl + 5 * 16384, fb2 + l * 128,
            WTG + 3 * 16384,
            MOD + 1024 + l * 1024, MOD + 4096 + l * 1024,
            fin ? (float*)d_out : Vbuf, fin);
    }
}

// Round 22
// 180.644 us; speedup vs baseline: 1.2263x; 1.2263x over previous
//
#include <hip/hip_runtime.h>
#include <hip/hip_bf16.h>

#define DEV static __device__ __forceinline__

typedef __bf16 bf16x8 __attribute__((ext_vector_type(8)));
typedef unsigned short u16x8 __attribute__((ext_vector_type(8)));
typedef unsigned short u16x4 __attribute__((ext_vector_type(4)));
typedef float f32x4 __attribute__((ext_vector_type(4)));

#if __has_builtin(__builtin_amdgcn_exp2f)
#define EXP2F(x) __builtin_amdgcn_exp2f(x)
#else
#define EXP2F(x) exp2f(x)
#endif
#if __has_builtin(__builtin_amdgcn_rcpf)
#define RCPF(x) __builtin_amdgcn_rcpf(x)
#else
#define RCPF(x) (1.0f / (x))
#endif

// ---------- helpers ----------

DEV unsigned short f2bfh(float f) {
    return __builtin_bit_cast(unsigned short, (__bf16)f);
}

DEV float bf2f(unsigned short v) {
    return __builtin_bit_cast(float, (unsigned)v << 16);
}

DEV float gelu_f(float x) {
    float x2 = x * x;
    float t  = __builtin_fmaf(-0.10294324f, x2, -2.3022082f);
    float e  = EXP2F(x * t);
    return x * RCPF(1.0f + e);
}

DEV f32x4 mfma16(bf16x8 a, bf16x8 b, f32x4 c) {
    return __builtin_amdgcn_mfma_f32_16x16x32_bf16(a, b, c, 0, 0, 0);
}

DEV bf16x8 cvt8(float4 x, float4 y) {
    bf16x8 r;
    r[0] = (__bf16)x.x; r[1] = (__bf16)x.y; r[2] = (__bf16)x.z; r[3] = (__bf16)x.w;
    r[4] = (__bf16)y.x; r[5] = (__bf16)y.y; r[6] = (__bf16)y.z; r[7] = (__bf16)y.w;
    return r;
}

DEV bf16x8 aload_f32(const float* p) {
    float4 x = *(const float4*)p;
    float4 y = *(const float4*)(p + 4);
    return cvt8(x, y);
}

DEV bf16x8 uload(const unsigned short* p) {
    return __builtin_bit_cast(bf16x8, *(const u16x8*)(p));
}

DEV bf16x8 bload(const unsigned short* WT, int col, int koff) {
    return __builtin_bit_cast(bf16x8, *(const u16x8*)(WT + col * 136 + koff));
}

DEV void stage_wt(unsigned short* WT, const unsigned short* src, int tid, int nthr) {
    for (int i = tid; i < 2048; i += nthr) {
        int n = i >> 4, k0 = (i & 15) << 3;
        *(u16x8*)(WT + n * 136 + k0) = *(const u16x8*)(src + n * 128 + k0);
    }
}

// direct global -> LDS, 16 B per lane. Dest = wave-uniform base + lane*16.
DEV void gload16(const void* g, void* lds) {
    __builtin_amdgcn_global_load_lds(
        (const __attribute__((address_space(1))) unsigned*)g,
        (__attribute__((address_space(3))) unsigned*)lds, 16, 0, 0);
}

// ---------- weight pre-transpose ----------
__global__ __launch_bounds__(256) void k_wconv(
    const float* __restrict__ smW1, const float* __restrict__ smW2,
    const float* __restrict__ projW, const float* __restrict__ msgW1,
    const float* __restrict__ msgW2, const float* __restrict__ ffnW1,
    const float* __restrict__ ffnW2, unsigned short* __restrict__ WTG)
{
    int m = blockIdx.x >> 3;
    int chunk = blockIdx.x & 7;
    const float* src;
    if (m == 0) src = smW1;
    else if (m == 1) src = smW1 + 16384;
    else if (m == 2) src = smW2;
    else if (m == 3) src = projW;
    else {
        int mm = m - 4; int l = mm / 6; int j = mm % 6;
        if (j < 3)      src = msgW1 + l * 49152 + j * 16384;
        else if (j == 3) src = msgW2 + l * 16384;
        else if (j == 4) src = ffnW1 + l * 16384;
        else             src = ffnW2 + l * 16384;
    }
    unsigned short* dst = WTG + m * 16384;
    int s0 = chunk * 2048 + threadIdx.x * 8;
    int k = s0 >> 7, n = s0 & 127;
    float4 x = *(const float4*)(src + s0);
    float4 y = *(const float4*)(src + s0 + 4);
    dst[(n + 0) * 128 + k] = f2bfh(x.x);
    dst[(n + 1) * 128 + k] = f2bfh(x.y);
    dst[(n + 2) * 128 + k] = f2bfh(x.z);
    dst[(n + 3) * 128 + k] = f2bfh(x.w);
    dst[(n + 4) * 128 + k] = f2bfh(y.x);
    dst[(n + 5) * 128 + k] = f2bfh(y.y);
    dst[(n + 6) * 128 + k] = f2bfh(y.z);
    dst[(n + 7) * 128 + k] = f2bfh(y.w);
}

// ---------- time features + adaLN modulation ----------
__global__ __launch_bounds__(256) void k_prep(
    const float* __restrict__ t,
    const float* __restrict__ smadaW, const float* __restrict__ smadab,
    const float* __restrict__ a1W, const float* __restrict__ a1b,
    const float* __restrict__ a2W, const float* __restrict__ a2b,
    float* __restrict__ MOD)
{
    __shared__ float tf[4][128];
    int tid = threadIdx.x;
    {
        int b = tid >> 6, i = tid & 63;
        float wn = __expf(-(float)i * (9.210340371976184f / 64.0f));
        float ph = t[b] * wn;
        tf[b][2 * i]     = sinf(ph);
        tf[b][2 * i + 1] = cosf(ph);
    }
    __syncthreads();
    int o = blockIdx.x * 256 + tid;
    int b, c;
    const float* W; const float* bias; float* out;
    if (o < 1024) {
        b = o >> 8; c = o & 255; W = smadaW; bias = smadab; out = MOD + o;
    } else if (o < 4096) {
        int oo = o - 1024; int lb = oo >> 8; int l = lb >> 2;
        b = lb & 3; c = oo & 255;
        W = a1W + l * 32768; bias = a1b + l * 256; out = MOD + o;
    } else {
        int oo = o - 4096; int lb = oo >> 8; int l = lb >> 2;
        b = lb & 3; c = oo & 255;
        W = a2W + l * 32768; bias = a2b + l * 256; out = MOD + 4096 + oo;
    }
    float s = bias[c];
    const float* tfb = tf[b];
    #pragma unroll 8
    for (int k = 0; k < 128; ++k) s += tfb[k] * W[k * 256 + c];
    *out = s;
}

// ---------- sequence messenger MLP + adaLN -> Vbuf ----------
__global__ __launch_bounds__(256) void k_msgr(
    const float* __restrict__ V, const float* __restrict__ Z,
    const unsigned short* __restrict__ WTG,
    const float* __restrict__ smb1, const float* __restrict__ smb2,
    const float* __restrict__ MOD, float* __restrict__ Vout)
{
    __shared__ __align__(16) unsigned short WT[128 * 136];
    __shared__ __align__(16) float XB[64 * 132];
    const int tid = threadIdx.x;
    const int w = tid >> 6, l = tid & 63, lr = l & 15, lg = l >> 4;
    const int tok0 = blockIdx.x * 64;
    const int batch = tok0 >> 11;
    const int rowA = tok0 + w * 16 + lr;

    f32x4 acc[8] = {};
    for (int kh = 0; kh < 2; ++kh) {
        __syncthreads();
        stage_wt(WT, WTG + kh * 16384, tid, 256);
        __syncthreads();
        const float* A = (kh == 0) ? V : Z;
        #pragma unroll
        for (int ks = 0; ks < 4; ++ks) {
            bf16x8 a = aload_f32(A + rowA * 128 + ks * 32 + lg * 8);
            #pragma unroll
            for (int c = 0; c < 8; ++c)
                acc[c] = mfma16(a, bload(WT, c * 16 + lr, ks * 32 + lg * 8), acc[c]);
        }
    }
    #pragma unroll
    for (int c = 0; c < 8; ++c) {
        int col = c * 16 + lr;
        float b1v = smb1[col];
        #pragma unroll
        for (int j = 0; j < 4; ++j)
            XB[(w * 16 + lg * 4 + j) * 132 + col] = gelu_f(acc[c][j] + b1v);
    }
    __syncthreads();
    stage_wt(WT, WTG + 2 * 16384, tid, 256);
    __syncthreads();
    f32x4 acc2[8] = {};
    #pragma unroll
    for (int ks = 0; ks < 4; ++ks) {
        bf16x8 a = aload_f32(XB + (w * 16 + lr) * 132 + ks * 32 + lg * 8);
        #pragma unroll
        for (int c = 0; c < 8; ++c)
            acc2[c] = mfma16(a, bload(WT, c * 16 + lr, ks * 32 + lg * 8), acc2[c]);
    }
    const float* MODp = MOD + batch * 256;
    #pragma unroll
    for (int j = 0; j < 4; ++j) {
        int row = tok0 + w * 16 + lg * 4 + j;
        float xv[8], s1 = 0.f, s2 = 0.f;
        #pragma unroll
        for (int c = 0; c < 8; ++c) {
            int col = c * 16 + lr;
            float x = acc2[c][j] + smb2[col] + V[row * 128 + col];
            xv[c] = x; s1 += x; s2 += x * x;
        }
        #pragma unroll
        for (int m = 1; m <= 8; m <<= 1) { s1 += __shfl_xor(s1, m); s2 += __shfl_xor(s2, m); }
        float mu = s1 * (1.0f / 128.0f);
        float var = s2 * (1.0f / 128.0f) - mu * mu;
        float rs = rsqrtf(var + 1e-5f);
        #pragma unroll
        for (int c = 0; c < 8; ++c) {
            int col = c * 16 + lr;
            Vout[row * 128 + col] = (xv[c] - mu) * rs * (1.0f + MODp[col]) + MODp[128 + col];
        }
    }
}

// ---------- per-layer: TA = V@W1a + b1 (f32) OR TB = V@W1c (bf16) ----------
// Grid 256: blocks 0-127 compute TA, blocks 128-255 compute TB.
__global__ __launch_bounds__(256) void k_tab(
    const float* __restrict__ Vb, const unsigned short* __restrict__ WTa,
    const unsigned short* __restrict__ WTc, const float* __restrict__ b1,
    float* __restrict__ TAf, unsigned short* __restrict__ TBb)
{
    __shared__ __align__(16) unsigned short WT[128 * 136];
    const int tid = threadIdx.x;
    const int w = tid >> 6, l = tid & 63, lr = l & 15, lg = l >> 4;
    const int half = blockIdx.x >> 7;                 // 0: TA, 1: TB
    const int tok0 = (blockIdx.x & 127) * 64;
    const int rowA = tok0 + w * 16 + lr;

    stage_wt(WT, half ? WTc : WTa, tid, 256);
    __syncthreads();
    f32x4 acc[8] = {};
    #pragma unroll
    for (int ks = 0; ks < 4; ++ks) {
        bf16x8 a = aload_f32(Vb + rowA * 128 + ks * 32 + lg * 8);
        #pragma unroll
        for (int c = 0; c < 8; ++c)
            acc[c] = mfma16(a, bload(WT, c * 16 + lr, ks * 32 + lg * 8), acc[c]);
    }
    if (half == 0) {
        #pragma unroll
        for (int c = 0; c < 8; ++c) {
            int col = c * 16 + lr;
            float b1v = b1[col];
            #pragma unroll
            for (int j = 0; j < 4; ++j) {
                int row = tok0 + w * 16 + lg * 4 + j;
                TAf[row * 128 + col] = acc[c][j] + b1v;
            }
        }
    } else {
        #pragma unroll
        for (int c = 0; c < 8; ++c) {
            int col = c * 16 + lr;
            #pragma unroll
            for (int j = 0; j < 4; ++j) {
                int row = tok0 + w * 16 + lg * 4 + j;
                TBb[row * 128 + col] = f2bfh(acc[c][j]);
            }
        }
    }
}

// ---------- PRODUCTION edge kernel (R18/R20 best): counted-vmcnt dbuf (MODE 3) ----------
// Grid 2048 x 4 tok, double buffer, launch_bounds(256,2).
// MODE 3: Kidx for all 4 tokens prefetched to registers; per step
// {issue loads(i+1); s_waitcnt vmcnt(4); s_barrier; compute(i); s_barrier}.
// MODE 1 (layer 0, reg-staged E + PLAIN bf16 Ebf writeback) keeps __syncthreads.
template<int MODE>
__global__ __launch_bounds__(256, 2) void k_edge16(
    const float* __restrict__ E,              // f32 [8192][30][128]
    const unsigned short* __restrict__ Ebf,   // bf16 PLAIN [8192][32][128] (MODE 3)
    unsigned short* __restrict__ EbfW,        // writeback target (MODE 1)
    const int* __restrict__ Kidx, const float* __restrict__ TAf,
    const unsigned short* __restrict__ TBb,   // bf16 PLAIN [8192][128]
    const unsigned short* __restrict__ WTb, float* __restrict__ S)
{
    __shared__ __align__(16) unsigned short ELb[2][32 * 128];   // 2 x 8192 B
    __shared__ __align__(16) unsigned short TBL[2][32 * 128];   // 2 x 8192 B
    const int tid = threadIdx.x;
    const int w = tid >> 6, l = tid & 63, lr = l & 15, lg = l >> 4;
    const int nq = w;
    const int t0 = blockIdx.x * 4;
    const int bbase = (t0 >> 11) << 11;

    // loop-invariant B fragments: cols [nq*32, nq*32+32), 32 VGPR, L2-hot
    bf16x8 bfr[8];
    #pragma unroll
    for (int n = 0; n < 2; ++n)
        #pragma unroll
        for (int ks = 0; ks < 4; ++ks)
            bfr[n * 4 + ks] = uload(WTb + (nq * 32 + n * 16 + lr) * 128 + ks * 32 + lg * 8);

    float4 eR[4];   // MODE<3 staging regs
    int kc[2];

    auto KREAD2 = [&](int tok, int k[2]) {
        #pragma unroll
        for (int it = 0; it < 2; ++it) {
            int r = (it * 256 + tid) >> 4;
            k[it] = (r < 30) ? Kidx[tok * 30 + r] : 0;
        }
    };
    auto TBGLOAD = [&](int buf, const int k[2]) {
        #pragma unroll
        for (int it = 0; it < 2; ++it) {
            int s = it * 256 + tid;
            int r = s >> 4, q = s & 15;
            const char* src = (const char*)(TBb + (size_t)(bbase + k[it]) * 128)
                            + (((q ^ (r & 7)) << 4));
            gload16(src, (char*)TBL[buf] + it * 4096 + (w << 10));
        }
    };
    auto EGLOAD = [&](int buf, int tok) {
        #pragma unroll
        for (int it = 0; it < 2; ++it) {
            int s = it * 256 + tid;
            int r = s >> 4, q = s & 15;
            const char* src = (const char*)Ebf + (size_t)tok * 8192 + r * 256
                            + (((q ^ (r & 7)) << 4));
            gload16(src, (char*)ELb[buf] + it * 4096 + (w << 10));
        }
    };
    auto EISSUE = [&](int tok) {
        #pragma unroll
        for (int it = 0; it < 4; ++it) {
            int s = it * 256 + tid;
            if (s < 960)
                eR[it] = *(const float4*)(E + ((size_t)tok * 30 + (s >> 5)) * 128 + (s & 31) * 4);
        }
    };
    auto SWRITE_E = [&](int buf, int tok) {
        #pragma unroll
        for (int it = 0; it < 4; ++it) {
            int s = it * 256 + tid;
            if (s < 960) {
                int rr = s >> 5, q = s & 31;
                u16x4 pk;
                pk[0] = f2bfh(eR[it].x); pk[1] = f2bfh(eR[it].y);
                pk[2] = f2bfh(eR[it].z); pk[3] = f2bfh(eR[it].w);
                *(u16x4*)((char*)ELb[buf] + rr * 256 + ((q * 8) ^ ((rr & 7) << 4))) = pk;
                if constexpr (MODE == 1)
                    *(u16x4*)((char*)EbfW + (size_t)tok * 8192 + rr * 256 + q * 8) = pk;
            } else if constexpr (MODE == 1) {
                int rr = s >> 5, q = s & 31;
                u16x4 z = {0, 0, 0, 0};
                *(u16x4*)((char*)EbfW + (size_t)tok * 8192 + rr * 256 + q * 8) = z;
            }
        }
    };
    auto COMPUTE = [&](int tok, int cur) {
        float ta[2];
        #pragma unroll
        for (int n = 0; n < 2; ++n) ta[n] = TAf[tok * 128 + nq * 32 + n * 16 + lr];
        float sacc[2] = {0.f, 0.f};
        const char* eb  = (const char*)ELb[cur];
        const char* tbb = (const char*)TBL[cur];
        #pragma unroll
        for (int m = 0; m < 2; ++m) {
            bf16x8 ar[4];
            #pragma unroll
            for (int ks = 0; ks < 4; ++ks)
                ar[ks] = *(const bf16x8*)(eb + (m * 16 + lr) * 256 +
                          (((ks * 32 + lg * 8) * 2) ^ ((lr & 7) << 4)));
            f32x4 acc[2] = {};
            #pragma unroll
            for (int ks = 0; ks < 4; ++ks)
                #pragma unroll
                for (int n = 0; n < 2; ++n)
                    acc[n] = mfma16(ar[ks], bfr[n * 4 + ks], acc[n]);
            #pragma unroll
            for (int n = 0; n < 2; ++n) {
                int c2 = (nq * 32 + n * 16 + lr) * 2;
                #pragma unroll
                for (int j = 0; j < 4; ++j) {
                    int r = m * 16 + lg * 4 + j;
                    if (r < 30) {
                        unsigned short uv = *(const unsigned short*)(tbb + r * 256 + (c2 ^ ((r & 7) << 4)));
                        sacc[n] += gelu_f(acc[n][j] + ta[n] + bf2f(uv));
                    }
                }
            }
        }
        #pragma unroll
        for (int n = 0; n < 2; ++n) {
            sacc[n] += __shfl_xor(sacc[n], 16);
            sacc[n] += __shfl_xor(sacc[n], 32);
        }
        if (l < 16) {
            #pragma unroll
            for (int n = 0; n < 2; ++n)
                S[tok * 128 + nq * 32 + n * 16 + l] = sacc[n];
        }
    };

    if constexpr (MODE == 3) {
        // Kidx for all 4 tokens prefetched into registers (statically indexed)
        int k0[2], k1[2], k2[2], k3[2];
        KREAD2(t0 + 0, k0);
        KREAD2(t0 + 1, k1);
        KREAD2(t0 + 2, k2);
        KREAD2(t0 + 3, k3);
        EGLOAD(0, t0);
        TBGLOAD(0, k0);

#define EDGE_STEP(I, KNEXT, WAITSTR)                                     \
        {                                                                \
            if constexpr ((I) + 1 <= 3) {                                \
                TBGLOAD(((I) + 1) & 1, KNEXT);                           \
                EGLOAD(((I) + 1) & 1, t0 + (I) + 1);                     \
            }                                                            \
            asm volatile("s_waitcnt vmcnt(" WAITSTR ")" ::: "memory");   \
            __builtin_amdgcn_sched_barrier(0);                           \
            __builtin_amdgcn_s_barrier();                                \
            __builtin_amdgcn_sched_barrier(0);                           \
            COMPUTE(t0 + (I), (I) & 1);                                  \
            if constexpr ((I) < 3) {                                     \
                __builtin_amdgcn_sched_barrier(0);                       \
                __builtin_amdgcn_s_barrier();                            \
                __builtin_amdgcn_sched_barrier(0);                       \
            }                                                            \
        }
        EDGE_STEP(0, k1, "4")
        EDGE_STEP(1, k2, "4")
        EDGE_STEP(2, k3, "4")
        EDGE_STEP(3, k3, "0")
#undef EDGE_STEP
    } else {
        // ---- layer-0 path (reg-staged E + Ebf writeback): safe __syncthreads ----
        int ka[2];
        EISSUE(t0);
        KREAD2(t0, ka);
        SWRITE_E(0, t0);
        TBGLOAD(0, ka);
        EISSUE(t0 + 1);
        KREAD2(t0 + 1, kc);
        __syncthreads();

        #pragma unroll 1
        for (int i = 0; i < 4; ++i) {
            if (i + 1 <= 3) {
                int bufn = (i + 1) & 1;
                SWRITE_E(bufn, t0 + i + 1);
                TBGLOAD(bufn, kc);
                if (i + 2 <= 3) { EISSUE(t0 + i + 2); KREAD2(t0 + i + 2, kc); }
            }
            COMPUTE(t0 + i, i & 1);
            if (i < 3) __syncthreads();
        }
    }
}

// ---------- per-layer token kernel ----------
__global__ __launch_bounds__(256) void k_token(
    const float* __restrict__ Sb, const float* __restrict__ Vb,
    const unsigned short* __restrict__ WTW2, const float* __restrict__ b2,
    const unsigned short* __restrict__ WTF1, const float* __restrict__ fb1,
    const unsigned short* __restrict__ WTF2, const float* __restrict__ fb2,
    const unsigned short* __restrict__ WTP,
    const float* __restrict__ MOD1, const float* __restrict__ MOD2,
    float* __restrict__ Vout, int final_)
{
    __shared__ __align__(16) unsigned short WT[128 * 136];
    __shared__ __align__(16) float XB[64 * 132];
    const int tid = threadIdx.x;
    const int w = tid >> 6, l = tid & 63, lr = l & 15, lg = l >> 4;
    const int tok0 = blockIdx.x * 64;
    const int batch = tok0 >> 11;
    const int rloc = w * 16 + lr;

    stage_wt(WT, WTW2, tid, 256);
    __syncthreads();
    f32x4 acc[8] = {};
    #pragma unroll
    for (int ks = 0; ks < 4; ++ks) {
        bf16x8 a = aload_f32(Sb + (tok0 + rloc) * 128 + ks * 32 + lg * 8);
        #pragma unroll
        for (int c = 0; c < 8; ++c)
            acc[c] = mfma16(a, bload(WT, c * 16 + lr, ks * 32 + lg * 8), acc[c]);
    }
    const float* M1 = MOD1 + batch * 256;
    const float* M2 = MOD2 + batch * 256;
    float vp[8][4];
    #pragma unroll
    for (int j = 0; j < 4; ++j) {
        int row = tok0 + w * 16 + lg * 4 + j;
        float xv[8], s1 = 0.f, s2 = 0.f;
        #pragma unroll
        for (int c = 0; c < 8; ++c) {
            int col = c * 16 + lr;
            float x = acc[c][j] * (1.0f / 30.0f) + b2[col] + Vb[row * 128 + col];
            xv[c] = x; s1 += x; s2 += x * x;
        }
        #pragma unroll
        for (int m = 1; m <= 8; m <<= 1) { s1 += __shfl_xor(s1, m); s2 += __shfl_xor(s2, m); }
        float mu = s1 * (1.0f / 128.0f);
        float var = s2 * (1.0f / 128.0f) - mu * mu;
        float rs = rsqrtf(var + 1e-5f);
        #pragma unroll
        for (int c = 0; c < 8; ++c) {
            int col = c * 16 + lr;
            vp[c][j] = (xv[c] - mu) * rs * (1.0f + M1[col]) + M1[128 + col];
        }
    }
    __syncthreads();
    #pragma unroll
    for (int c = 0; c < 8; ++c)
        #pragma unroll
        for (int j = 0; j < 4; ++j)
            XB[(w * 16 + lg * 4 + j) * 132 + c * 16 + lr] = vp[c][j];
    stage_wt(WT, WTF1, tid, 256);
    __syncthreads();
    f32x4 accB[8] = {};
    #pragma unroll
    for (int ks = 0; ks < 4; ++ks) {
        bf16x8 a = aload_f32(XB + rloc * 132 + ks * 32 + lg * 8);
        #pragma unroll
        for (int c = 0; c < 8; ++c)
            accB[c] = mfma16(a, bload(WT, c * 16 + lr, ks * 32 + lg * 8), accB[c]);
    }
    __syncthreads();
    #pragma unroll
    for (int c = 0; c < 8; ++c) {
        int col = c * 16 + lr;
        float bv = fb1[col];
        #pragma unroll
        for (int j = 0; j < 4; ++j)
            XB[(w * 16 + lg * 4 + j) * 132 + col] = gelu_f(accB[c][j] + bv);
    }
    stage_wt(WT, WTF2, tid, 256);
    __syncthreads();
    f32x4 accC[8] = {};
    #pragma unroll
    for (int ks = 0; ks < 4; ++ks) {
        bf16x8 a = aload_f32(XB + rloc * 132 + ks * 32 + lg * 8);
        #pragma unroll
        for (int c = 0; c < 8; ++c)
            accC[c] = mfma16(a, bload(WT, c * 16 + lr, ks * 32 + lg * 8), accC[c]);
    }
    float v2[8][4];
    #pragma unroll
    for (int j = 0; j < 4; ++j) {
        float xv[8], s1 = 0.f, s2 = 0.f;
        #pragma unroll
        for (int c = 0; c < 8; ++c) {
            int col = c * 16 + lr;
            float x = accC[c][j] + fb2[col] + vp[c][j];
            xv[c] = x; s1 += x; s2 += x * x;
        }
        #pragma unroll
        for (int m = 1; m <= 8; m <<= 1) { s1 += __shfl_xor(s1, m); s2 += __shfl_xor(s2, m); }
        float mu = s1 * (1.0f / 128.0f);
        float var = s2 * (1.0f / 128.0f) - mu * mu;
        float rs = rsqrtf(var + 1e-5f);
        #pragma unroll
        for (int c = 0; c < 8; ++c) {
            int col = c * 16 + lr;
            v2[c][j] = (xv[c] - mu) * rs * (1.0f + M2[col]) + M2[128 + col];
        }
    }
    if (!final_) {
        #pragma unroll
        for (int c = 0; c < 8; ++c)
            #pragma unroll
            for (int j = 0; j < 4; ++j)
                Vout[(tok0 + w * 16 + lg * 4 + j) * 128 + c * 16 + lr] = v2[c][j];
    } else {
        __syncthreads();
        #pragma unroll
        for (int c = 0; c < 8; ++c)
            #pragma unroll
            for (int j = 0; j < 4; ++j)
                XB[(w * 16 + lg * 4 + j) * 132 + c * 16 + lr] = v2[c][j];
        stage_wt(WT, WTP, tid, 256);
        __syncthreads();
        f32x4 accD[8] = {};
        #pragma unroll
        for (int ks = 0; ks < 4; ++ks) {
            bf16x8 a = aload_f32(XB + rloc * 132 + ks * 32 + lg * 8);
            #pragma unroll
            for (int c = 0; c < 8; ++c)
                accD[c] = mfma16(a, bload(WT, c * 16 + lr, ks * 32 + lg * 8), accD[c]);
        }
        #pragma unroll
        for (int c = 0; c < 8; ++c)
            #pragma unroll
            for (int j = 0; j < 4; ++j)
                Vout[(tok0 + w * 16 + lg * 4 + j) * 128 + c * 16 + lr] = accD[c][j];
    }
}

// ---------- host ----------

extern "C" void kernel_launch(void* const* d_in, const int* in_sizes, int n_in,
                              void* d_out, int out_size, void* d_ws, size_t ws_size,
                              hipStream_t stream)
{
    const float* V     = (const float*)d_in[0];
    const float* E     = (const float*)d_in[1];
    const int*   K     = (const int*)d_in[2];
    const float* Z     = (const float*)d_in[3];
    const float* t     = (const float*)d_in[4];
    const float* smW1   = (const float*)d_in[6];
    const float* smb1   = (const float*)d_in[7];
    const float* smW2   = (const float*)d_in[8];
    const float* smb2   = (const float*)d_in[9];
    const float* smadaW = (const float*)d_in[10];
    const float* smadab = (const float*)d_in[11];
    const float* msgW1  = (const float*)d_in[12];
    const float* msgb1  = (const float*)d_in[13];
    const float* msgW2  = (const float*)d_in[14];
    const float* msgb2  = (const float*)d_in[15];
    const float* a1W    = (const float*)d_in[16];
    const float* a1b    = (const float*)d_in[17];
    const float* fW1    = (const float*)d_in[18];
    const float* fb1    = (const float*)d_in[19];
    const float* fW2    = (const float*)d_in[20];
    const float* fb2    = (const float*)d_in[21];
    const float* a2W    = (const float*)d_in[22];
    const float* a2b    = (const float*)d_in[23];
    const float* projW  = (const float*)d_in[24];

    float* Vbuf = (float*)d_ws;                            // 8192*128 f32
    float* TAf  = Vbuf + 8192 * 128;                       // 8192*128 f32
    float* Sb   = TAf + 8192 * 128;                        // 8192*128 f32
    float* MOD  = Sb + 8192 * 128;                         // 7168 f32
    unsigned short* TBb = (unsigned short*)(MOD + 7168);   // 8192*128 u16
    unsigned short* WTG = TBb + 8192 * 128;                // 22*16384 u16
    unsigned short* Ebf = WTG + 22 * 16384;                // 8192*4096 u16 (64 MB)

    size_t need = (size_t)(3 * 8192 * 128 + 7168) * 4
                + (size_t)(8192 * 128 + 22 * 16384) * 2
                + (size_t)8192 * 4096 * 2;
    const bool ebf_ok = (ws_size >= need);

    k_wconv<<<dim3(176), dim3(256), 0, stream>>>(smW1, smW2, projW, msgW1, msgW2, fW1, fW2, WTG);
    k_prep<<<dim3(28), dim3(256), 0, stream>>>(t, smadaW, smadab, a1W, a1b, a2W, a2b, MOD);
    k_msgr<<<dim3(128), dim3(256), 0, stream>>>(V, Z, WTG, smb1, smb2, MOD, Vbuf);

    for (int l = 0; l < 3; ++l) {
        const unsigned short* Wl = WTG + (4 + l * 6) * 16384;
        k_tab<<<dim3(256), dim3(256), 0, stream>>>(Vbuf, Wl, Wl + 2 * 16384, msgb1 + l * 128, TAf, TBb);
        if (ebf_ok) {
            if (l == 0)
                k_edge16<1><<<dim3(2048), dim3(256), 0, stream>>>(
                    E, Ebf, Ebf, K, TAf, TBb, Wl + 16384, Sb);
            else
                k_edge16<3><<<dim3(2048), dim3(256), 0, stream>>>(
                    E, Ebf, Ebf, K, TAf, TBb, Wl + 16384, Sb);
        } else {
            k_edge16<0><<<dim3(2048), dim3(256), 0, stream>>>(
                E, Ebf, Ebf, K, TAf, TBb, Wl + 16384, Sb);
        }
        int fin = (l == 2);
        k_token<<<dim3(128), dim3(256), 0, stream>>>(
            Sb, Vbuf, Wl + 3 * 16384, msgb2 + l * 128,
            Wl + 4 * 16384, fb1 + l * 128, Wl + 5 * 16384, fb2 + l * 128,
            WTG + 3 * 16384,
            MOD + 1024 + l * 1024, MOD + 4096 + l * 1024,
            fin ? (float*)d_out : Vbuf, fin);
    }
}